// Round 8
// baseline (66.976 us; speedup 1.0000x reference)
//
#include <hip/hip_runtime.h>
#include <hip/hip_bf16.h>

typedef __attribute__((ext_vector_type(8))) short short8;
typedef __attribute__((ext_vector_type(8))) unsigned short u16x8;
typedef __attribute__((ext_vector_type(4))) float f32x4;

constexpr int NB = 64;     // batch
constexpr int NL = 96;     // time / conv channels
constexpr int NC = 2048;   // feature / conv spatial
constexpr int TT = 64;     // conv spatial tile per block
constexpr int KTOT = 288;  // conv GEMM K = 96 ch * 3 taps, k = tau*96 + i
constexpr int LROW = 104;  // conv LDS row pitch (bf16)
constexpr float LOG2E = 1.44269504088896340736f;

__device__ inline unsigned short f2bf(float f) {
    union { float f; unsigned u; } v; v.f = f;
    unsigned r = v.u + 0x7fff + ((v.u >> 16) & 1);   // RNE
    return (unsigned short)(r >> 16);
}
__device__ inline unsigned cvt_pk_bf16(float lo, float hi) {
    unsigned r;
    asm("v_cvt_pk_bf16_f32 %0, %1, %2" : "=v"(r) : "v"(lo), "v"(hi));
    return r;
}
__device__ inline float fexp2(float x) {
    float r; asm("v_exp_f32 %0, %1" : "=v"(r) : "v"(x)); return r;
}
__device__ inline float frcp(float x) {
    float r; asm("v_rcp_f32 %0, %1" : "=v"(r) : "v"(x)); return r;
}
__device__ inline float bflo(unsigned d) { return __uint_as_float(d << 16); }
__device__ inline float bfhi(unsigned d) { return __uint_as_float(d & 0xffff0000u); }

// ---------------------------------------------------------------------------
// Weight permute+convert: Aw[o][k], k = tau*96 + i, bf16.
// ---------------------------------------------------------------------------
__global__ void prep_aw(const float* __restrict__ w, unsigned short* __restrict__ aw)
{
    int idx = blockIdx.x * 256 + threadIdx.x;
    if (idx >= NL * KTOT) return;
    int o = idx / KTOT, k = idx - o * KTOT;
    int tau = k / NL, i = k - tau * NL;
    aw[idx] = f2bf(w[(o * NL + i) * 3 + tau]);
}

// ---------------------------------------------------------------------------
// decompT phase C worker: quarter Q of one c-row. Input: the row's packed
// bf16 pairs (dwords) from LDS -> registers (static window range, clamped
// indices = replicate pad). Output: res/mm quarter, dense 48 B stores.
// ---------------------------------------------------------------------------
template<int Q>
__device__ __forceinline__ void winq(
    const unsigned* __restrict__ srow,    // &sxb[c][0] (49-dw row)
    unsigned short* __restrict__ rp,      // &resT[(b*NC+c)*NL]
    unsigned short* __restrict__ mp,
    float w0, float w1, float w2, float b0, float b1, float b2)
{
    constexpr int L0 = Q * 24;
    constexpr int DW0 = (Q == 0) ? 0 : (Q == 1) ? 6 : (Q == 2) ? 18 : 30;
    constexpr int NDW = (Q == 0 || Q == 3) ? 18 : 24;

    unsigned dv[NDW];
#pragma unroll
    for (int d = 0; d < NDW; ++d) dv[d] = srow[DW0 + d];

#define CLMP(r) ((r) < 0 ? 0 : ((r) > 95 ? 95 : (r)))
#define VAL(r) ((CLMP(r) & 1) ? bfhi(dv[(CLMP(r) >> 1) - DW0]) \
                              : bflo(dv[(CLMP(r) >> 1) - DW0]))

    float s5 = 0.0f, s13 = 0.0f, s25 = 0.0f;
#pragma unroll
    for (int d = -12; d <= 12; ++d) {
        float v = VAL(L0 + d);
        s25 += v;
        if (d >= -6 && d <= 6) s13 += v;
        if (d >= -2 && d <= 2) s5 += v;
    }

    unsigned rd[12], md[12];
    float pr = 0.0f, pm = 0.0f;
#pragma unroll
    for (int i = 0; i < 24; ++i) {
        const int l = L0 + i;
        if (i > 0) {
            s25 += VAL(l + 12) - VAL(l - 13);
            s13 += VAL(l + 6)  - VAL(l - 7);
            s5  += VAL(l + 2)  - VAL(l - 3);
        }
        float xl = VAL(l);
        float e0 = fexp2(fmaf(xl, w0, b0));
        float e1 = fexp2(fmaf(xl, w1, b1));
        float e2 = fexp2(fmaf(xl, w2, b2));
        float inv = frcp(e0 + e1 + e2);
        float mmv = fmaf(s5 * 0.2f, e0,
                    fmaf(s13 * (1.0f / 13.0f), e1,
                         s25 * 0.04f * e2)) * inv;
        float rv = xl - mmv;
        if ((i & 1) == 0) { pr = rv; pm = mmv; }
        else {
            rd[i >> 1] = cvt_pk_bf16(pr, rv);
            md[i >> 1] = cvt_pk_bf16(pm, mmv);
        }
    }
#undef VAL
#undef CLMP

#pragma unroll
    for (int v = 0; v < 3; ++v) {
        union { u16x8 vv; unsigned d[4]; } o;
        o.d[0] = rd[v*4]; o.d[1] = rd[v*4+1]; o.d[2] = rd[v*4+2]; o.d[3] = rd[v*4+3];
        *(u16x8*)(rp + L0 + v * 8) = o.vv;
        o.d[0] = md[v*4]; o.d[1] = md[v*4+1]; o.d[2] = md[v*4+2]; o.d[3] = md[v*4+3];
        *(u16x8*)(mp + L0 + v * 8) = o.vv;
    }
}

// ---------------------------------------------------------------------------
// decompT: transpose + decompose, block = (b, 64-c tile), 256 thr, 38.7 KB
// LDS -> 4 blocks/CU. A: coalesced float4 stage [96 l][64 c]. B: conflict-
// free transpose+cvt_pk -> packed rows [64 c][48 dw]. C: per-(c, quarter)
// register sliding windows, dense global stores. No spills, no long chains.
// ---------------------------------------------------------------------------
__global__ __launch_bounds__(256, 4) void decompT(
    const float* __restrict__ x,
    const float* __restrict__ gw,
    const float* __restrict__ gb,
    unsigned short* __restrict__ resT,   // [64][2048][96] bf16
    unsigned short* __restrict__ mmT)
{
    __shared__ float sxf[96][68];        // pitch 68: 16B-aligned rows
    __shared__ unsigned sxb[64][49];     // packed bf16 pairs; 49 odd -> conflict-free

    int b = blockIdx.x;
    int c0 = blockIdx.y * 64;
    size_t xb = (size_t)b * NL * NC;

    // ---- Phase A: stage x tile (float4, fully coalesced) ----
    for (int u = threadIdx.x; u < 96 * 16; u += 256) {
        int row = u >> 4, cq = u & 15;
        f32x4 v = *(const f32x4*)(x + xb + (size_t)row * NC + c0 + cq * 4);
        *(f32x4*)(&sxf[row][cq * 4]) = v;
    }
    __syncthreads();

    // ---- Phase B: transpose + convert (stride-1 reads, odd-pitch writes) ----
    {
        int c = threadIdx.x & 63, lq = threadIdx.x >> 6;   // lq = 24-l strip
#pragma unroll
        for (int m = 0; m < 12; ++m) {
            int l = lq * 24 + m * 2;
            sxb[c][lq * 12 + m] = cvt_pk_bf16(sxf[l][c], sxf[l + 1][c]);
        }
    }
    __syncthreads();

    // ---- Phase C: sliding windows per (c, quarter); q wave-uniform ----
    {
        int c = threadIdx.x & 63, q = threadIdx.x >> 6;
        unsigned short* rp = resT + ((size_t)b * NC + c0 + c) * NL;
        unsigned short* mp = mmT  + ((size_t)b * NC + c0 + c) * NL;
        float w0 = gw[0] * LOG2E, w1 = gw[1] * LOG2E, w2 = gw[2] * LOG2E;
        float b0 = gb[0] * LOG2E, b1 = gb[1] * LOG2E, b2 = gb[2] * LOG2E;
        const unsigned* srow = &sxb[c][0];
        if (q == 0)      winq<0>(srow, rp, mp, w0, w1, w2, b0, b1, b2);
        else if (q == 1) winq<1>(srow, rp, mp, w0, w1, w2, b0, b1, b2);
        else if (q == 2) winq<2>(srow, rp, mp, w0, w1, w2, b0, b1, b2);
        else             winq<3>(srow, rp, mp, w0, w1, w2, b0, b1, b2);
    }
}

// ---------------------------------------------------------------------------
// Conv: both circular convs as one bf16 MFMA GEMM (R1-proven).
//   out[o][t] = sum_k Aw[o][k] * B[k][t],  B[k=tau*96+i][t] = X[i][t+tau-1]
// ---------------------------------------------------------------------------
__global__ __launch_bounds__(256) void conv_mfma(
    const unsigned short* __restrict__ resT,
    const unsigned short* __restrict__ mmT,
    const unsigned short* __restrict__ aw,
    float* __restrict__ out0,
    float* __restrict__ out1)
{
    __shared__ unsigned short sx[2][TT + 2][LROW];

    int b = blockIdx.x;
    int t0 = blockIdx.y * TT;
    size_t xb = (size_t)b * NC * NL;

    for (int idx = threadIdx.x; idx < 2 * (TT + 2) * 12; idx += 256) {
        int sig = idx / ((TT + 2) * 12);
        int rem = idx - sig * (TT + 2) * 12;
        int row = rem / 12, ch = rem - row * 12;
        int t = (t0 - 1 + row) & (NC - 1);
        const unsigned short* src = sig ? mmT : resT;
        u16x8 v = *(const u16x8*)(src + xb + (size_t)t * NL + ch * 8);
        *(u16x8*)(&sx[sig][row][ch * 8]) = v;
    }

    int lane = threadIdx.x & 63;
    int wv = threadIdx.x >> 6;
    int mg = wv & 1, ng = wv >> 1;
    int lr = lane & 15, lk = lane >> 4;

    f32x4 acc[3][2][2] = {};

    const unsigned short* abase = aw + (size_t)(mg * 48 + lr) * KTOT + lk * 8;
    short8 aCur[3], aNxt[3];
#pragma unroll
    for (int mt = 0; mt < 3; ++mt)
        aCur[mt] = *(const short8*)(abase + mt * 16 * KTOT);

    __syncthreads();

#pragma unroll
    for (int ks = 0; ks < 9; ++ks) {
        if (ks < 8) {
#pragma unroll
            for (int mt = 0; mt < 3; ++mt)
                aNxt[mt] = *(const short8*)(abase + mt * 16 * KTOT + (ks + 1) * 32);
        }
        const int tau = ks / 3;
        const int i0 = (ks - tau * 3) * 32;
        short8 bf[2][2];
#pragma unroll
        for (int nt = 0; nt < 2; ++nt) {
            int r = ng * 32 + nt * 16 + lr + tau;
#pragma unroll
            for (int sig = 0; sig < 2; ++sig)
                bf[nt][sig] = *(const short8*)(&sx[sig][r][i0 + lk * 8]);
        }
#pragma unroll
        for (int mt = 0; mt < 3; ++mt)
#pragma unroll
            for (int nt = 0; nt < 2; ++nt)
#pragma unroll
                for (int sig = 0; sig < 2; ++sig)
                    acc[mt][nt][sig] = __builtin_amdgcn_mfma_f32_16x16x32_bf16(
                        aCur[mt], bf[nt][sig], acc[mt][nt][sig], 0, 0, 0);
#pragma unroll
        for (int mt = 0; mt < 3; ++mt) aCur[mt] = aNxt[mt];
    }

    size_t ob = (size_t)b * NL * NC;
    int tw = t0 + ng * 32 + lr;
#pragma unroll
    for (int mt = 0; mt < 3; ++mt) {
        int o0 = mg * 48 + mt * 16 + lk * 4;
#pragma unroll
        for (int nt = 0; nt < 2; ++nt) {
#pragma unroll
            for (int r4 = 0; r4 < 4; ++r4) {
                out0[ob + (size_t)(o0 + r4) * NC + tw + nt * 16] = acc[mt][nt][0][r4];
                out1[ob + (size_t)(o0 + r4) * NC + tw + nt * 16] = acc[mt][nt][1][r4];
            }
        }
    }
}

extern "C" void kernel_launch(void* const* d_in, const int* in_sizes, int n_in,
                              void* d_out, int out_size, void* d_ws, size_t ws_size,
                              hipStream_t stream)
{
    const float* x      = (const float*)d_in[0];
    const float* conv_w = (const float*)d_in[1];
    const float* gate_w = (const float*)d_in[2];
    const float* gate_b = (const float*)d_in[3];

    float* out0 = (float*)d_out;
    float* out1 = out0 + (size_t)NB * NL * NC;

    unsigned short* resT = (unsigned short*)d_ws;          // [64][2048][96] bf16
    unsigned short* mmT  = resT + (size_t)NB * NC * NL;
    unsigned short* awb  = mmT  + (size_t)NB * NC * NL;    // [96][288] bf16

    prep_aw<<<dim3((NL * KTOT + 255) / 256), 256, 0, stream>>>(conv_w, awb);
    decompT<<<dim3(NB, NC / 64), 256, 0, stream>>>(x, gate_w, gate_b, resT, mmT);
    conv_mfma<<<dim3(NB, NC / TT), 256, 0, stream>>>(resT, mmT, awb, out0, out1);
}

// Round 9
// 51.058 us; speedup vs baseline: 1.3118x; 1.3118x over previous
//
#include <hip/hip_runtime.h>
#include <hip/hip_bf16.h>

typedef __attribute__((ext_vector_type(8))) short short8;
typedef __attribute__((ext_vector_type(8))) unsigned short u16x8;
typedef __attribute__((ext_vector_type(4))) unsigned short u16x4;
typedef __attribute__((ext_vector_type(4))) float f32x4;

constexpr int NB = 64;     // batch
constexpr int NL = 96;     // time / conv channels
constexpr int NC = 2048;   // feature / conv spatial
constexpr int TT = 64;     // conv spatial tile per block
constexpr int KTOT = 288;  // conv GEMM K = 96 ch * 3 taps, k = tau*96 + i
constexpr int LROW = 104;  // LDS row pitch in bf16 (52 dw, 16B-aligned rows)
constexpr float LOG2E = 1.44269504088896340736f;

__device__ inline unsigned short f2bf(float f) {
    union { float f; unsigned u; } v; v.f = f;
    unsigned r = v.u + 0x7fff + ((v.u >> 16) & 1);   // RNE
    return (unsigned short)(r >> 16);
}
__device__ inline unsigned cvt_pk_bf16(float lo, float hi) {
    unsigned r;
    asm("v_cvt_pk_bf16_f32 %0, %1, %2" : "=v"(r) : "v"(lo), "v"(hi));
    return r;
}
__device__ inline float fexp2(float x) {
    float r; asm("v_exp_f32 %0, %1" : "=v"(r) : "v"(x)); return r;
}
__device__ inline float frcp(float x) {
    float r; asm("v_rcp_f32 %0, %1" : "=v"(r) : "v"(x)); return r;
}
__device__ inline float bflo(unsigned d) { return __uint_as_float(d << 16); }
__device__ inline float bfhi(unsigned d) { return __uint_as_float(d & 0xffff0000u); }

// ---------------------------------------------------------------------------
// Weight permute+convert: Aw[o][k], k = tau*96 + i, bf16.
// ---------------------------------------------------------------------------
__global__ void prep_aw(const float* __restrict__ w, unsigned short* __restrict__ aw)
{
    int idx = blockIdx.x * 256 + threadIdx.x;
    if (idx >= NL * KTOT) return;
    int o = idx / KTOT, k = idx - o * KTOT;
    int tau = k / NL, i = k - tau * NL;
    aw[idx] = f2bf(w[(o * NL + i) * 3 + tau]);
}

// ---------------------------------------------------------------------------
// winq<Q>: sliding-window decomp for quarter Q (l = 24Q..24Q+23) of one
// column. Reads <=24 packed-bf16 dwords from the staged LDS row into
// registers (static indices, clamp = replicate pad), computes the three
// moving means + softmax gate, writes mm (bf16) back to the mm LDS row.
// Live set ~40 VGPR -> no spill. R8-validated index math.
// ---------------------------------------------------------------------------
template<int Q>
__device__ __forceinline__ void winq(
    const unsigned* __restrict__ srow,     // &sx[0][c][0], 52-dw row
    unsigned short* __restrict__ mrow,     // &sx[1][c][0]
    float w0, float w1, float w2, float b0, float b1, float b2)
{
    constexpr int L0 = Q * 24;
    constexpr int DW0 = (Q == 0) ? 0 : 12 * Q - 6;
    constexpr int NDW = (Q == 0 || Q == 3) ? 18 : 24;

    unsigned dv[NDW];
#pragma unroll
    for (int d = 0; d < NDW; ++d) dv[d] = srow[DW0 + d];

#define CLMP(r) ((r) < 0 ? 0 : ((r) > 95 ? 95 : (r)))
#define VAL(r) ((CLMP(r) & 1) ? bfhi(dv[(CLMP(r) >> 1) - DW0]) \
                              : bflo(dv[(CLMP(r) >> 1) - DW0]))

    float s5 = 0.0f, s13 = 0.0f, s25 = 0.0f;
#pragma unroll
    for (int d = -12; d <= 12; ++d) {
        float v = VAL(L0 + d);
        s25 += v;
        if (d >= -6 && d <= 6) s13 += v;
        if (d >= -2 && d <= 2) s5 += v;
    }

    unsigned md[12];
    float pm = 0.0f;
#pragma unroll
    for (int i = 0; i < 24; ++i) {
        const int l = L0 + i;
        if (i > 0) {
            s25 += VAL(l + 12) - VAL(l - 13);
            s13 += VAL(l + 6)  - VAL(l - 7);
            s5  += VAL(l + 2)  - VAL(l - 3);
        }
        float xl = VAL(l);
        float e0 = fexp2(fmaf(xl, w0, b0));
        float e1 = fexp2(fmaf(xl, w1, b1));
        float e2 = fexp2(fmaf(xl, w2, b2));
        float inv = frcp(e0 + e1 + e2);
        float mmv = fmaf(s5 * 0.2f, e0,
                    fmaf(s13 * (1.0f / 13.0f), e1,
                         s25 * 0.04f * e2)) * inv;
        if ((i & 1) == 0) pm = mmv;
        else              md[i >> 1] = cvt_pk_bf16(pm, mmv);
    }
#undef VAL
#undef CLMP

#pragma unroll
    for (int v = 0; v < 6; ++v) {
        union { u16x4 vv; unsigned d[2]; } o;
        o.d[0] = md[2 * v]; o.d[1] = md[2 * v + 1];
        *(u16x4*)(mrow + L0 + 4 * v) = o.vv;   // 8B-aligned
    }
}

// ---------------------------------------------------------------------------
// Fused kernel, block = (batch b, 64-wide spatial tile), 256 thr, 27.5 KB:
//  Phase 0: stage x -> packed bf16 LDS sx[0][c][l] via ALIGNED float4 row
//           reads + vertical cvt_pk (cols 1..64); edge cols 0,65 scalar.
//  Phase 1: winq per (c = lane, Q = wave) -- spill-free sliding windows;
//           edge cols 64/65 by lanes 0/32 of each wave (Q stays uniform).
//           Writes only mm (out0 recovered by linearity in the epilogue).
//  Phase 2: both convs as one bf16 MFMA GEMM over tiles {x, mm};
//           out1 = C(mm), out0 = C(x) - C(mm).
// ---------------------------------------------------------------------------
__global__ __launch_bounds__(256, 4) void fused2(
    const float* __restrict__ x,
    const float* __restrict__ gw,
    const float* __restrict__ gb,
    const unsigned short* __restrict__ aw,
    float* __restrict__ out0,
    float* __restrict__ out1)
{
    __shared__ __align__(16) unsigned short sx[2][TT + 2][LROW];  // [0]=x,[1]=mm

    int b = blockIdx.x;
    int t0 = blockIdx.y * TT;
    size_t xb = (size_t)b * NL * NC;

    int lane = threadIdx.x & 63;
    int wv = threadIdx.x >> 6;
    int lr = lane & 15, lk = lane >> 4;

    // ---- Phase 0: stage x -> sx[0] ----
    // main: 768 units (cq 0..15, l2 0..47): cols c=1+4cq+j <- aligned float4
    for (int u = threadIdx.x; u < 768; u += 256) {
        int cq = u >> 6 >> 0; cq = u / 48; int l2 = u - cq * 48;
        const float* p0 = x + xb + (size_t)(2 * l2) * NC + t0 + 4 * cq;
        f32x4 a = *(const f32x4*)p0;
        f32x4 bv = *(const f32x4*)(p0 + NC);
#pragma unroll
        for (int j = 0; j < 4; ++j)
            *(unsigned*)(&sx[0][1 + 4 * cq + j][2 * l2]) = cvt_pk_bf16(a[j], bv[j]);
    }
    // edges: c=0 (t=t0-1), c=65 (t=t0+64), circular
    for (int u = threadIdx.x; u < 96; u += 256) {
        int e = u / 48, l2 = u - e * 48;
        int t = e ? ((t0 + TT) & (NC - 1)) : ((t0 - 1) & (NC - 1));
        int c = e ? 65 : 0;
        const float* p0 = x + xb + (size_t)(2 * l2) * NC + t;
        *(unsigned*)(&sx[0][c][2 * l2]) = cvt_pk_bf16(p0[0], p0[NC]);
    }
    __syncthreads();

    // ---- Phase 1: spill-free sliding-window decomp -> sx[1] (mm only) ----
    {
        float w0 = gw[0] * LOG2E, w1 = gw[1] * LOG2E, w2 = gw[2] * LOG2E;
        float b0 = gb[0] * LOG2E, b1 = gb[1] * LOG2E, b2 = gb[2] * LOG2E;
        int c = lane;                     // 0..63
        const unsigned* srow = (const unsigned*)&sx[0][c][0];
        unsigned short* mrow = &sx[1][c][0];
        if (wv == 0)      winq<0>(srow, mrow, w0, w1, w2, b0, b1, b2);
        else if (wv == 1) winq<1>(srow, mrow, w0, w1, w2, b0, b1, b2);
        else if (wv == 2) winq<2>(srow, mrow, w0, w1, w2, b0, b1, b2);
        else              winq<3>(srow, mrow, w0, w1, w2, b0, b1, b2);
        // edge columns 64,65: lanes 0 and 32 of each wave, Q = wave (uniform)
        if ((lane & 31) == 0) {
            int ce = 64 + (lane >> 5);
            const unsigned* se = (const unsigned*)&sx[0][ce][0];
            unsigned short* me = &sx[1][ce][0];
            if (wv == 0)      winq<0>(se, me, w0, w1, w2, b0, b1, b2);
            else if (wv == 1) winq<1>(se, me, w0, w1, w2, b0, b1, b2);
            else if (wv == 2) winq<2>(se, me, w0, w1, w2, b0, b1, b2);
            else              winq<3>(se, me, w0, w1, w2, b0, b1, b2);
        }
    }

    // main-GEMM A prefetch (L2-hot 55 KB), issued before the barrier
    int mg = wv & 1, ng = wv >> 1;
    const unsigned short* abase = aw + (size_t)(mg * 48 + lr) * KTOT + lk * 8;
    short8 aCur[3], aNxt[3];
#pragma unroll
    for (int mt = 0; mt < 3; ++mt)
        aCur[mt] = *(const short8*)(abase + mt * 16 * KTOT);

    __syncthreads();

    // ---- Phase 2: conv GEMM over B-tiles {sx[0]=x, sx[1]=mm} ----
    f32x4 acc[3][2][2] = {};

#pragma unroll
    for (int ks = 0; ks < 9; ++ks) {
        if (ks < 8) {
#pragma unroll
            for (int mt = 0; mt < 3; ++mt)
                aNxt[mt] = *(const short8*)(abase + mt * 16 * KTOT + (ks + 1) * 32);
        }
        const int tau = ks / 3;
        const int i0 = (ks - tau * 3) * 32;
        short8 bfx[2], bfm[2];
#pragma unroll
        for (int nt = 0; nt < 2; ++nt) {
            int r = ng * 32 + nt * 16 + lr + tau;   // LDS row = local t + tau (<=65)
            bfx[nt] = *(const short8*)(&sx[0][r][i0 + lk * 8]);
            bfm[nt] = *(const short8*)(&sx[1][r][i0 + lk * 8]);
        }
#pragma unroll
        for (int mt = 0; mt < 3; ++mt)
#pragma unroll
            for (int nt = 0; nt < 2; ++nt) {
                acc[mt][nt][0] = __builtin_amdgcn_mfma_f32_16x16x32_bf16(
                    aCur[mt], bfx[nt], acc[mt][nt][0], 0, 0, 0);
                acc[mt][nt][1] = __builtin_amdgcn_mfma_f32_16x16x32_bf16(
                    aCur[mt], bfm[nt], acc[mt][nt][1], 0, 0, 0);
            }
#pragma unroll
        for (int mt = 0; mt < 3; ++mt) aCur[mt] = aNxt[mt];
    }

    // epilogue: C/D layout col = lane&15 (t), row = (lane>>4)*4 + reg (o)
    // out1 = C(mm); out0 = C(x) - C(mm)
    int tw = t0 + ng * 32 + lr;
#pragma unroll
    for (int mt = 0; mt < 3; ++mt) {
        int o0 = mg * 48 + mt * 16 + lk * 4;
#pragma unroll
        for (int nt = 0; nt < 2; ++nt) {
#pragma unroll
            for (int r4 = 0; r4 < 4; ++r4) {
                size_t idx = xb + (size_t)(o0 + r4) * NC + tw + nt * 16;
                float vm = acc[mt][nt][1][r4];
                out1[idx] = vm;
                out0[idx] = acc[mt][nt][0][r4] - vm;
            }
        }
    }
}

extern "C" void kernel_launch(void* const* d_in, const int* in_sizes, int n_in,
                              void* d_out, int out_size, void* d_ws, size_t ws_size,
                              hipStream_t stream)
{
    const float* x      = (const float*)d_in[0];
    const float* conv_w = (const float*)d_in[1];
    const float* gate_w = (const float*)d_in[2];
    const float* gate_b = (const float*)d_in[3];

    float* out0 = (float*)d_out;
    float* out1 = out0 + (size_t)NB * NL * NC;

    unsigned short* awb = (unsigned short*)d_ws;   // [96][288] bf16

    prep_aw<<<dim3((NL * KTOT + 255) / 256), 256, 0, stream>>>(conv_w, awb);
    fused2<<<dim3(NB, NC / TT), 256, 0, stream>>>(x, gate_w, gate_b, awb, out0, out1);
}

// Round 10
// 43.957 us; speedup vs baseline: 1.5237x; 1.1615x over previous
//
#include <hip/hip_runtime.h>
#include <hip/hip_bf16.h>

typedef __attribute__((ext_vector_type(8))) short short8;
typedef __attribute__((ext_vector_type(8))) unsigned short u16x8;
typedef __attribute__((ext_vector_type(4))) unsigned short u16x4;
typedef __attribute__((ext_vector_type(4))) float f32x4;

constexpr int NB = 64;     // batch
constexpr int NL = 96;     // time / conv channels
constexpr int NC = 2048;   // feature / conv spatial
constexpr int TT = 64;     // conv spatial tile per block
constexpr int KTOT = 288;  // conv GEMM K = 96 ch * 3 taps, k = tau*96 + i
constexpr int LROW = 104;  // LDS row pitch in bf16 (52 dw, 16B-aligned rows)
constexpr float LOG2E = 1.44269504088896340736f;

__device__ inline unsigned short f2bf(float f) {
    union { float f; unsigned u; } v; v.f = f;
    unsigned r = v.u + 0x7fff + ((v.u >> 16) & 1);   // RNE
    return (unsigned short)(r >> 16);
}
__device__ inline unsigned cvt_pk_bf16(float lo, float hi) {
    unsigned r;
    asm("v_cvt_pk_bf16_f32 %0, %1, %2" : "=v"(r) : "v"(lo), "v"(hi));
    return r;
}
__device__ inline float fexp2(float x) {
    float r; asm("v_exp_f32 %0, %1" : "=v"(r) : "v"(x)); return r;
}
__device__ inline float frcp(float x) {
    float r; asm("v_rcp_f32 %0, %1" : "=v"(r) : "v"(x)); return r;
}
__device__ inline float bflo(unsigned d) { return __uint_as_float(d << 16); }
__device__ inline float bfhi(unsigned d) { return __uint_as_float(d & 0xffff0000u); }

// ---------------------------------------------------------------------------
// Weight permute+convert: Aw[o][k], k = tau*96 + i, bf16.
// ---------------------------------------------------------------------------
__global__ void prep_aw(const float* __restrict__ w, unsigned short* __restrict__ aw)
{
    int idx = blockIdx.x * 256 + threadIdx.x;
    if (idx >= NL * KTOT) return;
    int o = idx / KTOT, k = idx - o * KTOT;
    int tau = k / NL, i = k - tau * NL;
    aw[idx] = f2bf(w[(o * NL + i) * 3 + tau]);
}

// ---------------------------------------------------------------------------
// winq<Q>: spill-free sliding-window decomp for quarter Q (l = 24Q..24Q+23)
// of one column. <=24 packed-bf16 dwords -> registers (static indices,
// clamp = replicate pad), three moving means + softmax gate, mm -> LDS.
// ---------------------------------------------------------------------------
template<int Q>
__device__ __forceinline__ void winq(
    const unsigned* __restrict__ srow,     // &sx[0][c][0], 52-dw row
    unsigned short* __restrict__ mrow,     // &sx[1][c][0]
    float w0, float w1, float w2, float b0, float b1, float b2)
{
    constexpr int L0 = Q * 24;
    constexpr int DW0 = (Q == 0) ? 0 : 12 * Q - 6;
    constexpr int NDW = (Q == 0 || Q == 3) ? 18 : 24;

    unsigned dv[NDW];
#pragma unroll
    for (int d = 0; d < NDW; ++d) dv[d] = srow[DW0 + d];

#define CLMP(r) ((r) < 0 ? 0 : ((r) > 95 ? 95 : (r)))
#define VAL(r) ((CLMP(r) & 1) ? bfhi(dv[(CLMP(r) >> 1) - DW0]) \
                              : bflo(dv[(CLMP(r) >> 1) - DW0]))

    float s5 = 0.0f, s13 = 0.0f, s25 = 0.0f;
#pragma unroll
    for (int d = -12; d <= 12; ++d) {
        float v = VAL(L0 + d);
        s25 += v;
        if (d >= -6 && d <= 6) s13 += v;
        if (d >= -2 && d <= 2) s5 += v;
    }

    unsigned md[12];
    float pm = 0.0f;
#pragma unroll
    for (int i = 0; i < 24; ++i) {
        const int l = L0 + i;
        if (i > 0) {
            s25 += VAL(l + 12) - VAL(l - 13);
            s13 += VAL(l + 6)  - VAL(l - 7);
            s5  += VAL(l + 2)  - VAL(l - 3);
        }
        float xl = VAL(l);
        float e0 = fexp2(fmaf(xl, w0, b0));
        float e1 = fexp2(fmaf(xl, w1, b1));
        float e2 = fexp2(fmaf(xl, w2, b2));
        float inv = frcp(e0 + e1 + e2);
        float mmv = fmaf(s5 * 0.2f, e0,
                    fmaf(s13 * (1.0f / 13.0f), e1,
                         s25 * 0.04f * e2)) * inv;
        if ((i & 1) == 0) pm = mmv;
        else              md[i >> 1] = cvt_pk_bf16(pm, mmv);
    }
#undef VAL
#undef CLMP

#pragma unroll
    for (int v = 0; v < 6; ++v) {
        union { u16x4 vv; unsigned d[2]; } o;
        o.d[0] = md[2 * v]; o.d[1] = md[2 * v + 1];
        *(u16x4*)(mrow + L0 + 4 * v) = o.vv;   // 8B-aligned
    }
}

// ---------------------------------------------------------------------------
// Fused kernel, block = (batch b, 64-wide spatial tile), 256 thr, 27.5 KB:
//  Phase 0: stage x -> packed bf16 LDS sx[0][c][l]; lanes sweep COLUMNS so
//           each 16-lane group reads a 256 B contiguous row run.
//  Phase 1: winq per (c = lane, Q = wave) for cols 0..63; edge cols 64/65
//           computed brute-force by 192 threads (1 element each) -- no
//           masked whole-winq duplication. Writes only mm (linearity).
//  Phase 2: both convs as one bf16 MFMA GEMM over tiles {x, mm};
//           out1 = C(mm), out0 = C(x) - C(mm).
// ---------------------------------------------------------------------------
__global__ __launch_bounds__(256, 4) void fused3(
    const float* __restrict__ x,
    const float* __restrict__ gw,
    const float* __restrict__ gb,
    const unsigned short* __restrict__ aw,
    float* __restrict__ out0,
    float* __restrict__ out1)
{
    __shared__ __align__(16) unsigned short sx[2][TT + 2][LROW];  // [0]=x,[1]=mm

    int b = blockIdx.x;
    int t0 = blockIdx.y * TT;
    size_t xb = (size_t)b * NL * NC;

    int lane = threadIdx.x & 63;
    int wv = threadIdx.x >> 6;
    int lr = lane & 15, lk = lane >> 4;

    // ---- Phase 0: stage x -> sx[0] ----
    // main: 768 units (l2 0..47, cq 0..15); lanes sweep cq -> 256B runs
    for (int u = threadIdx.x; u < 768; u += 256) {
        int l2 = u >> 4, cq = u & 15;
        const float* p0 = x + xb + (size_t)(2 * l2) * NC + t0 + 4 * cq;
        f32x4 a = *(const f32x4*)p0;
        f32x4 bv = *(const f32x4*)(p0 + NC);
#pragma unroll
        for (int j = 0; j < 4; ++j)
            *(unsigned*)(&sx[0][1 + 4 * cq + j][2 * l2]) = cvt_pk_bf16(a[j], bv[j]);
    }
    // edges: c=0 (t=t0-1), c=65 (t=t0+64), circular
    if (threadIdx.x < 96) {
        int u = threadIdx.x;
        int e = u / 48, l2 = u - e * 48;
        int t = e ? ((t0 + TT) & (NC - 1)) : ((t0 - 1) & (NC - 1));
        int c = e ? 65 : 0;
        const float* p0 = x + xb + (size_t)(2 * l2) * NC + t;
        *(unsigned*)(&sx[0][c][2 * l2]) = cvt_pk_bf16(p0[0], p0[NC]);
    }
    __syncthreads();

    // ---- Phase 1: decomp -> sx[1] (mm only) ----
    {
        float w0 = gw[0] * LOG2E, w1 = gw[1] * LOG2E, w2 = gw[2] * LOG2E;
        float b0 = gb[0] * LOG2E, b1 = gb[1] * LOG2E, b2 = gb[2] * LOG2E;

        // main columns 0..63: c = lane, Q = wave (wave-uniform template)
        {
            const unsigned* srow = (const unsigned*)&sx[0][lane][0];
            unsigned short* mrow = &sx[1][lane][0];
            if (wv == 0)      winq<0>(srow, mrow, w0, w1, w2, b0, b1, b2);
            else if (wv == 1) winq<1>(srow, mrow, w0, w1, w2, b0, b1, b2);
            else if (wv == 2) winq<2>(srow, mrow, w0, w1, w2, b0, b1, b2);
            else              winq<3>(srow, mrow, w0, w1, w2, b0, b1, b2);
        }
        // edge columns 64,65: 192 threads, one element each (waves 0..2;
        // wave 3 skips entirely via execz -- no duplicated winq issue)
        if (threadIdx.x < 192) {
            int ce = 64 + (threadIdx.x & 1);
            int l  = threadIdx.x >> 1;            // 0..95
            const unsigned short* col = &sx[0][ce][0];
            float s5 = 0.0f, s13 = 0.0f, s25 = 0.0f;
#pragma unroll
            for (int d = -12; d <= 12; ++d) {
                int li = l + d; li = li < 0 ? 0 : (li > 95 ? 95 : li);
                float v = __uint_as_float(((unsigned)col[li]) << 16);
                s25 += v;
                if (d >= -6 && d <= 6) s13 += v;
                if (d >= -2 && d <= 2) s5 += v;
            }
            float xl = __uint_as_float(((unsigned)col[l]) << 16);
            float e0 = fexp2(fmaf(xl, w0, b0));
            float e1 = fexp2(fmaf(xl, w1, b1));
            float e2 = fexp2(fmaf(xl, w2, b2));
            float inv = frcp(e0 + e1 + e2);
            float mmv = fmaf(s5 * 0.2f, e0,
                        fmaf(s13 * (1.0f / 13.0f), e1,
                             s25 * 0.04f * e2)) * inv;
            sx[1][ce][l] = (unsigned short)(cvt_pk_bf16(mmv, mmv) & 0xffffu);
        }
    }

    // main-GEMM A prefetch (L2-hot 55 KB), issued before the barrier
    int mg = wv & 1, ng = wv >> 1;
    const unsigned short* abase = aw + (size_t)(mg * 48 + lr) * KTOT + lk * 8;
    short8 aCur[3], aNxt[3];
#pragma unroll
    for (int mt = 0; mt < 3; ++mt)
        aCur[mt] = *(const short8*)(abase + mt * 16 * KTOT);

    __syncthreads();

    // ---- Phase 2: conv GEMM over B-tiles {sx[0]=x, sx[1]=mm} ----
    f32x4 acc[3][2][2] = {};

#pragma unroll
    for (int ks = 0; ks < 9; ++ks) {
        if (ks < 8) {
#pragma unroll
            for (int mt = 0; mt < 3; ++mt)
                aNxt[mt] = *(const short8*)(abase + mt * 16 * KTOT + (ks + 1) * 32);
        }
        const int tau = ks / 3;
        const int i0 = (ks - tau * 3) * 32;
        short8 bfx[2], bfm[2];
#pragma unroll
        for (int nt = 0; nt < 2; ++nt) {
            int r = ng * 32 + nt * 16 + lr + tau;   // LDS row = local t + tau (<=65)
            bfx[nt] = *(const short8*)(&sx[0][r][i0 + lk * 8]);
            bfm[nt] = *(const short8*)(&sx[1][r][i0 + lk * 8]);
        }
#pragma unroll
        for (int mt = 0; mt < 3; ++mt)
#pragma unroll
            for (int nt = 0; nt < 2; ++nt) {
                acc[mt][nt][0] = __builtin_amdgcn_mfma_f32_16x16x32_bf16(
                    aCur[mt], bfx[nt], acc[mt][nt][0], 0, 0, 0);
                acc[mt][nt][1] = __builtin_amdgcn_mfma_f32_16x16x32_bf16(
                    aCur[mt], bfm[nt], acc[mt][nt][1], 0, 0, 0);
            }
#pragma unroll
        for (int mt = 0; mt < 3; ++mt) aCur[mt] = aNxt[mt];
    }

    // epilogue: C/D layout col = lane&15 (t), row = (lane>>4)*4 + reg (o)
    // out1 = C(mm); out0 = C(x) - C(mm)
    int tw = t0 + ng * 32 + lr;
#pragma unroll
    for (int mt = 0; mt < 3; ++mt) {
        int o0 = mg * 48 + mt * 16 + lk * 4;
#pragma unroll
        for (int nt = 0; nt < 2; ++nt) {
#pragma unroll
            for (int r4 = 0; r4 < 4; ++r4) {
                size_t idx = xb + (size_t)(o0 + r4) * NC + tw + nt * 16;
                float vm = acc[mt][nt][1][r4];
                out1[idx] = vm;
                out0[idx] = acc[mt][nt][0][r4] - vm;
            }
        }
    }
}

extern "C" void kernel_launch(void* const* d_in, const int* in_sizes, int n_in,
                              void* d_out, int out_size, void* d_ws, size_t ws_size,
                              hipStream_t stream)
{
    const float* x      = (const float*)d_in[0];
    const float* conv_w = (const float*)d_in[1];
    const float* gate_w = (const float*)d_in[2];
    const float* gate_b = (const float*)d_in[3];

    float* out0 = (float*)d_out;
    float* out1 = out0 + (size_t)NB * NL * NC;

    unsigned short* awb = (unsigned short*)d_ws;   // [96][288] bf16

    prep_aw<<<dim3((NL * KTOT + 255) / 256), 256, 0, stream>>>(conv_w, awb);
    fused3<<<dim3(NB, NC / TT), 256, 0, stream>>>(x, gate_w, gate_b, awb, out0, out1);
}